// Round 1
// baseline (365.398 us; speedup 1.0000x reference)
//
#include <hip/hip_runtime.h>
#include <stdint.h>
#include <stddef.h>

// Problem constants
#define IN_F   4096
#define OUT_F  14336
#define TOK    32

// Tiling
#define OTILE  64                 // output features per block (one per lane)
#define ISPLIT 4                  // grid.y split over the reduction dim
#define IBLK   (IN_F / ISPLIT)    // 1024 i per block
#define ICHUNK 64                 // i per LDS stage (64 int32 = 256 B per row)
#define NCHUNK (IBLK / ICHUNK)    // 16

typedef const __attribute__((address_space(1))) void* gas_ptr;
typedef __attribute__((address_space(3))) void* las_ptr;

// Kernel 1: xsT[i*32 + t] = x[t][i] * scales[i]  (tokens contiguous per i),
// and zero d_out (needed: harness poisons it, main kernel uses atomicAdd).
__global__ __launch_bounds__(256) void prep_kernel(
    const float* __restrict__ x, const float* __restrict__ scales,
    float* __restrict__ xsT, float* __restrict__ out)
{
    const int f = blockIdx.x * 256 + threadIdx.x;   // 0..131071 (grid 512)
    const int i = f >> 5;
    const int t = f & 31;
    // write coalesced; x reads are strided but L2-absorbed (x = 512 KB)
    xsT[f] = x[(size_t)t * IN_F + i] * scales[i];
    if (f < (OUT_F * TOK / 4)) {                    // 114688 float4 = 458752 floats
        ((float4*)out)[f] = make_float4(0.f, 0.f, 0.f, 0.f);
    }
}

// Main kernel: block = 4 waves; wave w owns tokens [8w, 8w+8); lane owns one
// output feature o = o0+lane. Weights go global->LDS via global_load_lds
// (width 16, XOR-16 swizzled source so the by-o ds_read_b128 is conflict-free).
// x-side operand is wave-uniform -> s_load into SGPRs, no LDS traffic.
__global__ __launch_bounds__(256, 4) void qgemm_kernel(
    const int* __restrict__ wgt, const float* __restrict__ xsT,
    float* __restrict__ out)
{
    __shared__ int lds[2][OTILE * ICHUNK];          // 2 x 16 KB
    const int lane = threadIdx.x & 63;
    const int wv   = __builtin_amdgcn_readfirstlane(threadIdx.x >> 6); // 0..3
    const int o0   = blockIdx.x * OTILE;
    const int ib0  = blockIdx.y * IBLK;
    const int lx   = lane & 15;

    float acc[8];
#pragma unroll
    for (int t = 0; t < 8; ++t) acc[t] = 0.f;

    // Stage chunk c of the 64x64 int32 weight tile into lds[buf].
    // One instr = 64 lanes x 16 B = 1 KB = 4 rows of 256 B.
    // LDS pos (row r, chunk16 j=lane&15) receives global chunk (j ^ (r&15)).
    auto stage = [&](int buf, int c) {
#pragma unroll
        for (int k = 0; k < 4; ++k) {
            const int m = wv * 4 + k;                // instr index 0..15
            const int r = m * 4 + (lane >> 4);       // row 0..63
            const int j = lx ^ (r & 15);             // swizzled source chunk
            const int* g = wgt + (size_t)(o0 + r) * IN_F
                               + (ib0 + c * ICHUNK) + (j << 2);
            int* l = &lds[buf][m * 256];             // +lane*16B added by HW
            __builtin_amdgcn_global_load_lds((gas_ptr)g, (las_ptr)l, 16, 0, 0);
        }
    };

    stage(0, 0);
    __syncthreads();

    int cur = 0;
    for (int c = 0; c < NCHUNK; ++c) {
        if (c + 1 < NCHUNK) stage(cur ^ 1, c + 1);   // prefetch next chunk

        const int* row = &lds[cur][lane * ICHUNK];
        const float* xs_base = xsT + (size_t)(ib0 + c * ICHUNK) * TOK + wv * 8;
#pragma unroll
        for (int q = 0; q < 16; ++q) {
            // un-swizzle: global chunk q of my row sits at position q^lx
            const int4 wq = *(const int4*)(row + ((q ^ lx) << 2));
            const float f0 = (float)wq.x;
            const float f1 = (float)wq.y;
            const float f2 = (float)wq.z;
            const float f3 = (float)wq.w;
            // wave-uniform address -> s_load_dwordx8 per i (8 tokens)
            const float* xsp = xs_base + q * 4 * TOK;
#pragma unroll
            for (int t = 0; t < 8; ++t) {
                float a = acc[t];
                a = fmaf(f0, xsp[t],           a);
                a = fmaf(f1, xsp[TOK + t],     a);
                a = fmaf(f2, xsp[2 * TOK + t], a);
                a = fmaf(f3, xsp[3 * TOK + t], a);
                acc[t] = a;
            }
        }
        __syncthreads();   // drains staging vmcnt; next iter reads cur^1
        cur ^= 1;
    }

    // Each (token, o) gets ISPLIT partial sums -> fp32 atomics (out zeroed by prep)
#pragma unroll
    for (int t = 0; t < 8; ++t) {
        atomicAdd(&out[(size_t)(wv * 8 + t) * OUT_F + o0 + lane], acc[t]);
    }
}

extern "C" void kernel_launch(void* const* d_in, const int* in_sizes, int n_in,
                              void* d_out, int out_size, void* d_ws, size_t ws_size,
                              hipStream_t stream)
{
    const float* x      = (const float*)d_in[0];   // [32, 4096] fp32
    const int*   wgt    = (const int*)d_in[1];     // [14336, 4096] int32 (int8 vals)
    const float* scales = (const float*)d_in[2];   // [4096] fp32
    float* out = (float*)d_out;                    // [32, 14336] fp32
    float* xsT = (float*)d_ws;                     // 512 KB scratch

    prep_kernel<<<dim3((TOK * IN_F) / 256), 256, 0, stream>>>(x, scales, xsT, out);

    dim3 grid(OUT_F / OTILE, ISPLIT);              // 224 x 4 = 896 blocks
    qgemm_kernel<<<grid, 256, 0, stream>>>(wgt, xsT, out);
}

// Round 2
// 350.198 us; speedup vs baseline: 1.0434x; 1.0434x over previous
//
#include <hip/hip_runtime.h>
#include <stdint.h>
#include <stddef.h>

// Problem constants
#define IN_F   4096
#define OUT_F  14336
#define TOK    32

// Tiling
#define OTILE  64                 // output features per block (one per lane)
#define ISPLIT 8                  // grid.y split over the reduction dim
#define IBLK   (IN_F / ISPLIT)    // 512 i per block
#define ICHUNK 64                 // i per LDS stage (64 int32 = 256 B per row)
#define NCHUNK (IBLK / ICHUNK)    // 8

typedef const __attribute__((address_space(1))) void* gas_ptr;
typedef __attribute__((address_space(3))) void* las_ptr;

// Kernel 1: xsW[wv][i][t8] = x[8wv+t8][i] * scales[i]   ([4][4096][8] fp32, 512 KB)
// Per (wave, chunk) the qgemm x-operand is then 512 CONTIGUOUS wave-uniform
// floats -> s_load_dwordx16 streams. Also zeroes d_out (qgemm uses atomicAdd).
__global__ __launch_bounds__(256) void prep_kernel(
    const float* __restrict__ x, const float* __restrict__ scales,
    float* __restrict__ xsW, float* __restrict__ out)
{
    const int f = blockIdx.x * 256 + threadIdx.x;   // 0..131071 (grid 512)
    const int t = f >> 12;                          // 0..31 (coalesced x read)
    const int i = f & (IN_F - 1);
    const float v = x[f] * scales[i];
    // [wv][i][t&7]: scattered 32B-stride writes, 512 KB total, L2-absorbed
    xsW[(((size_t)(t >> 3) * IN_F) + i) * 8 + (t & 7)] = v;
    if (f < (OUT_F * TOK / 4)) {                    // zero 458752 floats
        ((float4*)out)[f] = make_float4(0.f, 0.f, 0.f, 0.f);
    }
}

// Main kernel: block = 4 waves; wave w owns tokens [8w, 8w+8); lane owns
// output feature o = o0+lane. Weights global->LDS via global_load_lds width=16
// (XOR-16 source swizzle so the by-o ds_read_b128 is 2-way-max on banks = free).
// x-side operand is wave-uniform -> SGPR s_loads, zero LDS traffic.
__global__ __launch_bounds__(256, 5) void qgemm_kernel(
    const int* __restrict__ wgt, const float* __restrict__ xsW,
    float* __restrict__ out)
{
    __shared__ int lds[2][OTILE * ICHUNK];          // 2 x 16 KB
    const int lane = threadIdx.x & 63;
    const int wv   = __builtin_amdgcn_readfirstlane(threadIdx.x >> 6); // 0..3
    const int o0   = blockIdx.x * OTILE;
    const int ib0  = blockIdx.y * IBLK;
    const int lx   = lane & 15;

    float acc[8];
#pragma unroll
    for (int t = 0; t < 8; ++t) acc[t] = 0.f;

    // Stage chunk c of the 64x64 int32 weight tile into lds[buf].
    // One instr = 64 lanes x 16 B = 1 KB = 4 rows of 256 B (contiguous global).
    // LDS slot (row r, chunk16 pos lx) receives global chunk lx^(r&15).
    auto stage = [&](int buf, int c) {
#pragma unroll
        for (int k = 0; k < 4; ++k) {
            const int m = wv * 4 + k;                // instr index 0..15
            const int r = m * 4 + (lane >> 4);       // row 0..63
            const int j = lx ^ (r & 15);             // swizzled source chunk
            const int* g = wgt + (size_t)(o0 + r) * IN_F
                               + (ib0 + c * ICHUNK) + (j << 2);
            int* l = &lds[buf][m * 256];             // +lane*16B added by HW
            __builtin_amdgcn_global_load_lds((gas_ptr)g, (las_ptr)l, 16, 0, 0);
        }
    };

    stage(0, 0);
    __syncthreads();

    int cur = 0;
    for (int c = 0; c < NCHUNK; ++c) {
        if (c + 1 < NCHUNK) stage(cur ^ 1, c + 1);   // prefetch next chunk

        const int* row = &lds[cur][lane * ICHUNK];
        // 512 contiguous wave-uniform floats for this (wave, chunk)
        const float* xw = xsW + (((size_t)wv * IN_F) + ib0 + c * ICHUNK) * 8;
#pragma unroll
        for (int q = 0; q < 16; ++q) {
            // un-swizzle: global chunk q of my row sits at LDS chunk q^lx
            const int4 wq = *(const int4*)(row + ((q ^ lx) << 2));
            const float f0 = (float)wq.x;
            const float f1 = (float)wq.y;
            const float f2 = (float)wq.z;
            const float f3 = (float)wq.w;
            const float* xp = xw + q * 32;           // 4 i x 8 t, contiguous
#pragma unroll
            for (int t = 0; t < 8; ++t) {
                float a = acc[t];
                a = fmaf(f0, xp[t],      a);
                a = fmaf(f1, xp[8 + t],  a);
                a = fmaf(f2, xp[16 + t], a);
                a = fmaf(f3, xp[24 + t], a);
                acc[t] = a;
            }
        }
        __syncthreads();   // drains staging vmcnt; next iter reads cur^1
        cur ^= 1;
    }

    // Each (token, o) gets ISPLIT partial sums -> fp32 atomics (out zeroed by prep)
#pragma unroll
    for (int t = 0; t < 8; ++t) {
        atomicAdd(&out[(size_t)(wv * 8 + t) * OUT_F + o0 + lane], acc[t]);
    }
}

extern "C" void kernel_launch(void* const* d_in, const int* in_sizes, int n_in,
                              void* d_out, int out_size, void* d_ws, size_t ws_size,
                              hipStream_t stream)
{
    const float* x      = (const float*)d_in[0];   // [32, 4096] fp32
    const int*   wgt    = (const int*)d_in[1];     // [14336, 4096] int32 (int8 vals)
    const float* scales = (const float*)d_in[2];   // [4096] fp32
    float* out = (float*)d_out;                    // [32, 14336] fp32
    float* xsW = (float*)d_ws;                     // 512 KB scratch

    prep_kernel<<<dim3((TOK * IN_F) / 256), 256, 0, stream>>>(x, scales, xsW, out);

    dim3 grid(OUT_F / OTILE, ISPLIT);              // 224 x 8 = 1792 blocks
    qgemm_kernel<<<grid, 256, 0, stream>>>(wgt, xsW, out);
}